// Round 1
// baseline (441.640 us; speedup 1.0000x reference)
//
#include <hip/hip_runtime.h>
#include <hip/hip_bf16.h>
#include <cstdint>
#include <cstddef>

// MHA: B=4, S=2048, D=1024, H=16, hd=64, causal. y = x @ W.T (W stored [e,d]).
// Pipeline: 3x proj GEMM (f32 in -> bf16 out) -> flash attn (bf16) -> out GEMM (bf16 -> f32).

typedef short bf16x8 __attribute__((ext_vector_type(8)));
typedef short short4v __attribute__((ext_vector_type(4)));
typedef float f32x4 __attribute__((ext_vector_type(4)));

__device__ __forceinline__ short f2bf(float f) {
    union { float f; uint32_t u; } c; c.f = f;
    uint32_t u = c.u;
    uint32_t r = u + 0x7fffu + ((u >> 16) & 1u);   // round-to-nearest-even
    return (short)(r >> 16);
}

// ---------------------------------------------------------------------------
// GEMM: Out[M=8192, N=1024] = A[8192,1024] * W[1024,1024]^T   (W row-major [n][k])
// 128x128 tile, BK=32, 256 threads = 4 waves (2x2), each wave 64x64 (4x4 frags).
// LDS padded to 40 shorts/row (80B, 16B-aligned groups, 2-way-free bank pattern).
// ---------------------------------------------------------------------------
template<bool A_IS_BF16, bool OUT_IS_F32>
__global__ __launch_bounds__(256) void gemm_kernel(const void* __restrict__ Ap,
                                                   const float* __restrict__ W,
                                                   void* __restrict__ Outp)
{
    __shared__ short As[128][40];
    __shared__ short Bs[128][40];
    const int tid  = threadIdx.x;
    const int lane = tid & 63;
    const int w    = tid >> 6;
    const int wr   = w >> 1, wc = w & 1;
    const int l15  = lane & 15;
    const int l4   = lane >> 4;
    const int m0   = blockIdx.y * 128;
    const int n0   = blockIdx.x * 128;

    f32x4 acc[4][4];
    const f32x4 zf = {0.f, 0.f, 0.f, 0.f};
    #pragma unroll
    for (int i = 0; i < 4; i++)
        #pragma unroll
        for (int j = 0; j < 4; j++) acc[i][j] = zf;

    for (int k0 = 0; k0 < 1024; k0 += 32) {
        // ---- stage A tile (128 x 32) ----
        if (A_IS_BF16) {
            const short* A = (const short*)Ap;
            #pragma unroll
            for (int i = 0; i < 2; i++) {
                int li = tid + i * 256;           // 512 chunks of 8 bf16
                int r = li >> 2, c = li & 3;
                bf16x8 v = *(const bf16x8*)&A[(size_t)(m0 + r) * 1024 + k0 + c * 8];
                *(bf16x8*)&As[r][c * 8] = v;
            }
        } else {
            const float* A = (const float*)Ap;
            #pragma unroll
            for (int i = 0; i < 4; i++) {
                int li = tid + i * 256;           // 1024 chunks of 4 f32
                int r = li >> 3, c = li & 7;
                const float4 v = *(const float4*)&A[(size_t)(m0 + r) * 1024 + k0 + c * 4];
                short4v s;
                s.x = f2bf(v.x); s.y = f2bf(v.y); s.z = f2bf(v.z); s.w = f2bf(v.w);
                *(short4v*)&As[r][c * 4] = s;
            }
        }
        // ---- stage B tile: W rows n0..n0+127, cols k0..k0+31 ----
        #pragma unroll
        for (int i = 0; i < 4; i++) {
            int li = tid + i * 256;
            int r = li >> 3, c = li & 7;
            const float4 v = *(const float4*)&W[(size_t)(n0 + r) * 1024 + k0 + c * 4];
            short4v s;
            s.x = f2bf(v.x); s.y = f2bf(v.y); s.z = f2bf(v.z); s.w = f2bf(v.w);
            *(short4v*)&Bs[r][c * 4] = s;
        }
        __syncthreads();

        bf16x8 af[4], bfr[4];
        #pragma unroll
        for (int mi = 0; mi < 4; mi++)
            af[mi] = *(const bf16x8*)&As[wr * 64 + mi * 16 + l15][l4 * 8];
        #pragma unroll
        for (int ni = 0; ni < 4; ni++)
            bfr[ni] = *(const bf16x8*)&Bs[wc * 64 + ni * 16 + l15][l4 * 8];
        #pragma unroll
        for (int mi = 0; mi < 4; mi++)
            #pragma unroll
            for (int ni = 0; ni < 4; ni++)
                acc[mi][ni] = __builtin_amdgcn_mfma_f32_16x16x32_bf16(af[mi], bfr[ni], acc[mi][ni], 0, 0, 0);
        __syncthreads();
    }

    // epilogue: C/D layout col = lane&15, row = (lane>>4)*4 + reg
    #pragma unroll
    for (int mi = 0; mi < 4; mi++) {
        #pragma unroll
        for (int ni = 0; ni < 4; ni++) {
            int row = m0 + wr * 64 + mi * 16 + (l4 << 2);
            int col = n0 + wc * 64 + ni * 16 + l15;
            #pragma unroll
            for (int j = 0; j < 4; j++) {
                float v = acc[mi][ni][j];
                if (OUT_IS_F32) ((float*)Outp)[(size_t)(row + j) * 1024 + col] = v;
                else            ((short*)Outp)[(size_t)(row + j) * 1024 + col] = f2bf(v);
            }
        }
    }
}

// ---------------------------------------------------------------------------
// Flash attention, causal. 1 wave/block. QBLK=32, KVBLK=32, hd=64.
// Q/K/V are bf16 [8192][1024]; per (b,h) row-stride 1024, head offset h*64.
// grid: (qt=64, bh=64), block 64.
// ---------------------------------------------------------------------------
__global__ __launch_bounds__(64) void attn_kernel(const short* __restrict__ Q,
                                                  const short* __restrict__ K,
                                                  const short* __restrict__ V,
                                                  short* __restrict__ A)
{
    __shared__ short P_lds[32][40];
    const int lane = threadIdx.x;
    const int l15  = lane & 15;
    const int l4   = lane >> 4;
    const int qt   = blockIdx.x;
    const int bh   = blockIdx.y;
    const int b    = bh >> 4, h = bh & 15;
    const int q0   = qt * 32;
    const size_t base = (size_t)b * 2048 * 1024 + (size_t)h * 64;
    const short* Qg = Q + base;
    const short* Kg = K + base;
    const short* Vg = V + base;

    // Q fragments: rows q0+rt*16+l15, k-dim d = kt*32 + l4*8 (+0..7)
    bf16x8 qf[2][2];
    #pragma unroll
    for (int rt = 0; rt < 2; rt++)
        #pragma unroll
        for (int kt = 0; kt < 2; kt++)
            qf[rt][kt] = *(const bf16x8*)&Qg[(size_t)(q0 + rt * 16 + l15) * 1024 + kt * 32 + l4 * 8];

    const f32x4 zf = {0.f, 0.f, 0.f, 0.f};
    f32x4 oacc[2][4];
    float m_s[2][4], l_s[2][4];
    #pragma unroll
    for (int rt = 0; rt < 2; rt++) {
        #pragma unroll
        for (int dt = 0; dt < 4; dt++) oacc[rt][dt] = zf;
        #pragma unroll
        for (int j = 0; j < 4; j++) { m_s[rt][j] = -1e30f; l_s[rt][j] = 0.f; }
    }

    for (int kvt = 0; kvt <= qt; ++kvt) {
        const int kv0 = kvt * 32;

        // K fragments (B-layout): n = kv = ct*16+l15, k = d = kt*32 + l4*8
        bf16x8 kf[2][2];
        #pragma unroll
        for (int ct = 0; ct < 2; ct++)
            #pragma unroll
            for (int kt = 0; kt < 2; kt++)
                kf[ct][kt] = *(const bf16x8*)&Kg[(size_t)(kv0 + ct * 16 + l15) * 1024 + kt * 32 + l4 * 8];

        f32x4 sacc[2][2];
        #pragma unroll
        for (int rt = 0; rt < 2; rt++)
            #pragma unroll
            for (int ct = 0; ct < 2; ct++) sacc[rt][ct] = zf;
        #pragma unroll
        for (int rt = 0; rt < 2; rt++)
            #pragma unroll
            for (int ct = 0; ct < 2; ct++)
                #pragma unroll
                for (int kt = 0; kt < 2; kt++)
                    sacc[rt][ct] = __builtin_amdgcn_mfma_f32_16x16x32_bf16(qf[rt][kt], kf[ct][kt], sacc[rt][ct], 0, 0, 0);

        // scale + causal mask (diagonal tile only: kv0 == q0)
        float s[2][2][4];
        const bool diag = (kvt == qt);
        #pragma unroll
        for (int rt = 0; rt < 2; rt++)
            #pragma unroll
            for (int ct = 0; ct < 2; ct++)
                #pragma unroll
                for (int j = 0; j < 4; j++) {
                    float v = sacc[rt][ct][j] * 0.125f;
                    if (diag && (ct * 16 + l15) > (rt * 16 + l4 * 4 + j)) v = -1e30f;
                    s[rt][ct][j] = v;
                }

        // online softmax: rows live in 16-lane groups sharing l4
        float p[2][2][4];
        #pragma unroll
        for (int rt = 0; rt < 2; rt++) {
            float sc[4];
            #pragma unroll
            for (int j = 0; j < 4; j++) {
                float pm = fmaxf(s[rt][0][j], s[rt][1][j]);
                #pragma unroll
                for (int msk = 1; msk < 16; msk <<= 1)
                    pm = fmaxf(pm, __shfl_xor(pm, msk));
                float m_new = fmaxf(m_s[rt][j], pm);
                sc[j] = __expf(m_s[rt][j] - m_new);
                float rs = 0.f;
                #pragma unroll
                for (int ct = 0; ct < 2; ct++) {
                    float pv = __expf(s[rt][ct][j] - m_new);
                    p[rt][ct][j] = pv;
                    rs += pv;
                }
                #pragma unroll
                for (int msk = 1; msk < 16; msk <<= 1)
                    rs += __shfl_xor(rs, msk);
                l_s[rt][j] = l_s[rt][j] * sc[j] + rs;
                m_s[rt][j] = m_new;
            }
            #pragma unroll
            for (int dt = 0; dt < 4; dt++)
                #pragma unroll
                for (int j = 0; j < 4; j++)
                    oacc[rt][dt][j] *= sc[j];
        }

        // P: C-layout -> LDS -> A-frag layout
        #pragma unroll
        for (int rt = 0; rt < 2; rt++)
            #pragma unroll
            for (int ct = 0; ct < 2; ct++)
                #pragma unroll
                for (int j = 0; j < 4; j++)
                    P_lds[rt * 16 + l4 * 4 + j][ct * 16 + l15] = f2bf(p[rt][ct][j]);
        __syncthreads();

        bf16x8 pf[2];
        #pragma unroll
        for (int rt = 0; rt < 2; rt++)
            pf[rt] = *(const bf16x8*)&P_lds[rt * 16 + l15][l4 * 8];

        // V fragments (B-layout): n = d = dt*16+l15, k = kv = l4*8 + j (scalar loads)
        bf16x8 vf[4];
        #pragma unroll
        for (int dt = 0; dt < 4; dt++)
            #pragma unroll
            for (int j = 0; j < 8; j++)
                vf[dt][j] = Vg[(size_t)(kv0 + l4 * 8 + j) * 1024 + dt * 16 + l15];

        #pragma unroll
        for (int rt = 0; rt < 2; rt++)
            #pragma unroll
            for (int dt = 0; dt < 4; dt++)
                oacc[rt][dt] = __builtin_amdgcn_mfma_f32_16x16x32_bf16(pf[rt], vf[dt], oacc[rt][dt], 0, 0, 0);
        __syncthreads();
    }

    // write O (bf16) into A_ws [8192][1024], col = h*64 + d
    #pragma unroll
    for (int rt = 0; rt < 2; rt++)
        #pragma unroll
        for (int dt = 0; dt < 4; dt++)
            #pragma unroll
            for (int j = 0; j < 4; j++) {
                int row = q0 + rt * 16 + l4 * 4 + j;
                int col = h * 64 + dt * 16 + l15;
                A[(size_t)(b * 2048 + row) * 1024 + col] = f2bf(oacc[rt][dt][j] / l_s[rt][j]);
            }
}

// ---------------------------------------------------------------------------
extern "C" void kernel_launch(void* const* d_in, const int* in_sizes, int n_in,
                              void* d_out, int out_size, void* d_ws, size_t ws_size,
                              hipStream_t stream)
{
    const float* x  = (const float*)d_in[0];
    const float* Wq = (const float*)d_in[1];
    const float* Wk = (const float*)d_in[2];
    const float* Wv = (const float*)d_in[3];
    const float* Wo = (const float*)d_in[4];
    float* out = (float*)d_out;

    const size_t SZ = (size_t)8192 * 1024;   // elements per [8192][1024] buffer
    short* Qw = (short*)d_ws;
    short* Kw = Qw + SZ;
    short* Vw = Kw + SZ;
    short* Aw = Vw + SZ;

    dim3 gg(8, 64), gb(256);
    hipLaunchKernelGGL((gemm_kernel<false, false>), gg, gb, 0, stream, (const void*)x, Wq, (void*)Qw);
    hipLaunchKernelGGL((gemm_kernel<false, false>), gg, gb, 0, stream, (const void*)x, Wk, (void*)Kw);
    hipLaunchKernelGGL((gemm_kernel<false, false>), gg, gb, 0, stream, (const void*)x, Wv, (void*)Vw);

    hipLaunchKernelGGL(attn_kernel, dim3(64, 64), dim3(64), 0, stream, Qw, Kw, Vw, Aw);

    hipLaunchKernelGGL((gemm_kernel<true, true>), gg, gb, 0, stream, (const void*)Aw, Wo, (void*)out);
}

// Round 3
// 384.497 us; speedup vs baseline: 1.1486x; 1.1486x over previous
//
#include <hip/hip_runtime.h>
#include <hip/hip_bf16.h>
#include <cstdint>
#include <cstddef>

// MHA B=4 S=2048 D=1024 H=16 hd=64 causal.
// Pipeline: convert x,W->bf16 | QKV GEMM (global_load_lds) | V transpose | flash attn (swapped QK^T) | out GEMM.
// Workspace: xb(16M) Wb(8M) Qw(16M) Kw(16M) = 56MB. Vw/Vt live in d_out halves; Aw aliases xb.

typedef short bf16x8 __attribute__((ext_vector_type(8)));
typedef float f32x4 __attribute__((ext_vector_type(4)));
typedef unsigned int u32x2 __attribute__((ext_vector_type(2)));

__device__ __forceinline__ short f2bf(float f) {
    union { float f; uint32_t u; } c; c.f = f;
    uint32_t r = c.u + 0x7fffu + ((c.u >> 16) & 1u);   // RNE
    return (short)(r >> 16);
}

__device__ __forceinline__ unsigned cvt_pk_bf16(float lo, float hi) {
    unsigned r;
    asm("v_cvt_pk_bf16_f32 %0, %1, %2" : "=v"(r) : "v"(lo), "v"(hi));
    return r;
}

#define GLOAD_LDS16(g, l) __builtin_amdgcn_global_load_lds( \
    (const __attribute__((address_space(1))) void*)(g),     \
    (__attribute__((address_space(3))) void*)(l), 16, 0, 0)

// ---------------------------------------------------------------------------
// f32 -> bf16 convert, 8 elems/thread
// ---------------------------------------------------------------------------
__global__ __launch_bounds__(256) void convert_kernel(const float* __restrict__ src,
                                                      short* __restrict__ dst) {
    int i = blockIdx.x * 256 + threadIdx.x;
    const float4* s = (const float4*)src + (size_t)i * 2;
    float4 v0 = s[0], v1 = s[1];
    bf16x8 o;
    o[0] = f2bf(v0.x); o[1] = f2bf(v0.y); o[2] = f2bf(v0.z); o[3] = f2bf(v0.w);
    o[4] = f2bf(v1.x); o[5] = f2bf(v1.y); o[6] = f2bf(v1.z); o[7] = f2bf(v1.w);
    *((bf16x8*)dst + i) = o;
}

// ---------------------------------------------------------------------------
// GEMM body: Out[gridDim.y*128, 1024] = A[., 1024](bf16) * Bw[1024,1024]^T (bf16)
// 128x128 tile, BK=32, 4 waves (2x2), global_load_lds staging (linear LDS).
// ---------------------------------------------------------------------------
template<bool OUT_F32>
__device__ __forceinline__ void gemm_body(const short* __restrict__ A,
                                          const short* __restrict__ Bw,
                                          void* __restrict__ Outp) {
    __shared__ short As[128 * 32];
    __shared__ short Bs[128 * 32];
    const int tid = threadIdx.x;
    const int lane = tid & 63, w = tid >> 6;
    const int wr = w >> 1, wc = w & 1;
    const int l15 = lane & 15, l4 = lane >> 4;
    const size_t m0 = (size_t)blockIdx.y * 128;
    const size_t n0 = (size_t)blockIdx.x * 128;

    f32x4 acc[4][4];
    const f32x4 zf = {0.f, 0.f, 0.f, 0.f};
    #pragma unroll
    for (int i = 0; i < 4; i++)
        #pragma unroll
        for (int j = 0; j < 4; j++) acc[i][j] = zf;

    for (int k0 = 0; k0 < 1024; k0 += 32) {
        #pragma unroll
        for (int r = 0; r < 2; r++) {
            int c = r * 256 + tid;
            int row = c >> 2, q = c & 3;
            GLOAD_LDS16(A  + (m0 + row) * 1024 + k0 + q * 8, &As[(r * 256 + w * 64) * 8]);
            GLOAD_LDS16(Bw + (n0 + row) * 1024 + k0 + q * 8, &Bs[(r * 256 + w * 64) * 8]);
        }
        __syncthreads();

        bf16x8 af[4], bfr[4];
        #pragma unroll
        for (int mi = 0; mi < 4; mi++)
            af[mi] = *(const bf16x8*)&As[(wr * 64 + mi * 16 + l15) * 32 + l4 * 8];
        #pragma unroll
        for (int ni = 0; ni < 4; ni++)
            bfr[ni] = *(const bf16x8*)&Bs[(wc * 64 + ni * 16 + l15) * 32 + l4 * 8];
        #pragma unroll
        for (int mi = 0; mi < 4; mi++)
            #pragma unroll
            for (int ni = 0; ni < 4; ni++)
                acc[mi][ni] = __builtin_amdgcn_mfma_f32_16x16x32_bf16(af[mi], bfr[ni], acc[mi][ni], 0, 0, 0);
        __syncthreads();
    }

    #pragma unroll
    for (int mi = 0; mi < 4; mi++) {
        #pragma unroll
        for (int ni = 0; ni < 4; ni++) {
            size_t row = m0 + wr * 64 + mi * 16 + (l4 << 2);
            size_t col = n0 + wc * 64 + ni * 16 + l15;
            #pragma unroll
            for (int j = 0; j < 4; j++) {
                float v = acc[mi][ni][j];
                if (OUT_F32) ((float*)Outp)[(row + j) * 1024 + col] = v;
                else         ((short*)Outp)[(row + j) * 1024 + col] = f2bf(v);
            }
        }
    }
}

__global__ __launch_bounds__(256) void gemm_qkv(const short* __restrict__ xb,
                                                const short* __restrict__ Wq,
                                                const short* __restrict__ Wk,
                                                const short* __restrict__ Wv,
                                                short* __restrict__ Q,
                                                short* __restrict__ K,
                                                short* __restrict__ V) {
    const short* Bw = (blockIdx.z == 0) ? Wq : (blockIdx.z == 1) ? Wk : Wv;
    short* Out      = (blockIdx.z == 0) ? Q  : (blockIdx.z == 1) ? K  : V;
    gemm_body<false>(xb, Bw, Out);
}

__global__ __launch_bounds__(256) void gemm_out(const short* __restrict__ Aw,
                                                const short* __restrict__ Wo,
                                                float* __restrict__ Out) {
    gemm_body<true>(Aw, Wo, Out);
}

// ---------------------------------------------------------------------------
// V transpose: Vt[(bh*64+d)*2048 + s] = Vw[(b*2048+s)*1024 + h*64 + d]
// 256 threads, 64x64 tile per block: each thread loads 16 shorts (full tile).
// ---------------------------------------------------------------------------
__global__ __launch_bounds__(256) void transpose_v(const short* __restrict__ Vw,
                                                   short* __restrict__ Vt) {
    __shared__ short T[64][72];
    const int tid = threadIdx.x;
    const int s0 = blockIdx.x * 64;
    const int bh = blockIdx.y, b = bh >> 4, h = bh & 15;
    const int r = tid >> 2, c = tid & 3;
    const size_t srow = (size_t)(b * 2048 + s0 + r) * 1024 + h * 64 + c * 16;
    *(bf16x8*)&T[r][c * 16]     = *(const bf16x8*)&Vw[srow];
    *(bf16x8*)&T[r][c * 16 + 8] = *(const bf16x8*)&Vw[srow + 8];
    __syncthreads();
    short tmp[16];
    #pragma unroll
    for (int i = 0; i < 16; i++) tmp[i] = T[c * 16 + i][r];
    bf16x8 o0, o1;
    #pragma unroll
    for (int i = 0; i < 8; i++) { o0[i] = tmp[i]; o1[i] = tmp[8 + i]; }
    size_t orow = (size_t)(bh * 64 + r) * 2048 + s0 + c * 16;
    *(bf16x8*)&Vt[orow] = o0;
    *(bf16x8*)&Vt[orow + 8] = o1;
}

// ---------------------------------------------------------------------------
// Flash attn, causal, swapped QK^T. 4 waves/block, each wave 32 q-rows.
// KVBLK=64. Q/K: [8192][1024] bf16; Vt: [bh*64+d][2048] bf16. grid (16, 64).
// ---------------------------------------------------------------------------
__global__ __launch_bounds__(256, 2) void attn_kernel(const short* __restrict__ Q,
                                                      const short* __restrict__ K,
                                                      const short* __restrict__ Vt,
                                                      short* __restrict__ Aout) {
    __shared__ short P_lds[4][32][72];
    const int tid = threadIdx.x;
    const int lane = tid & 63, w = tid >> 6;
    const int l15 = lane & 15, l4 = lane >> 4;
    const int qblk = 15 - blockIdx.x;               // heavy blocks first
    const int bh = blockIdx.y, b = bh >> 4, h = bh & 15;
    const int qw0 = qblk * 128 + w * 32;
    const short* Qg = Q + (size_t)b * 2048 * 1024 + h * 64;
    const short* Kg = K + (size_t)b * 2048 * 1024 + h * 64;
    const short* Vg = Vt + (size_t)bh * 64 * 2048;
    const float c1 = 0.18033688011112042f;          // 0.125 * log2(e)

    bf16x8 qfr[2][2];
    #pragma unroll
    for (int qf = 0; qf < 2; qf++)
        #pragma unroll
        for (int ks = 0; ks < 2; ks++)
            qfr[qf][ks] = *(const bf16x8*)&Qg[(size_t)(qw0 + qf * 16 + l15) * 1024 + ks * 32 + l4 * 8];

    const f32x4 zf = {0.f, 0.f, 0.f, 0.f};
    f32x4 oacc[4][2];                               // [df][qf]: O^T[d][q]
    float m_s[2] = {-3e38f, -3e38f}, l_s[2] = {0.f, 0.f};
    #pragma unroll
    for (int df = 0; df < 4; df++)
        #pragma unroll
        for (int qf = 0; qf < 2; qf++) oacc[df][qf] = zf;

    const int lim = (qw0 + 31) >> 6;
    for (int kvt = 0; kvt <= lim; ++kvt) {
        const int kv0 = kvt * 64;

        // S^T = K * Q^T : D[kv][q]
        f32x4 sacc[4][2];
        #pragma unroll
        for (int kvf = 0; kvf < 4; kvf++)
            #pragma unroll
            for (int qf = 0; qf < 2; qf++) sacc[kvf][qf] = zf;
        #pragma unroll
        for (int kvf = 0; kvf < 4; kvf++) {
            bf16x8 kf0 = *(const bf16x8*)&Kg[(size_t)(kv0 + kvf * 16 + l15) * 1024 + l4 * 8];
            bf16x8 kf1 = *(const bf16x8*)&Kg[(size_t)(kv0 + kvf * 16 + l15) * 1024 + 32 + l4 * 8];
            #pragma unroll
            for (int qf = 0; qf < 2; qf++) {
                sacc[kvf][qf] = __builtin_amdgcn_mfma_f32_16x16x32_bf16(kf0, qfr[qf][0], sacc[kvf][qf], 0, 0, 0);
                sacc[kvf][qf] = __builtin_amdgcn_mfma_f32_16x16x32_bf16(kf1, qfr[qf][1], sacc[kvf][qf], 0, 0, 0);
            }
        }

        if (kvt == lim) {                           // causal mask (last tile only)
            #pragma unroll
            for (int kvf = 0; kvf < 4; kvf++)
                #pragma unroll
                for (int qf = 0; qf < 2; qf++)
                    #pragma unroll
                    for (int j = 0; j < 4; j++) {
                        int kvg = kv0 + kvf * 16 + l4 * 4 + j;
                        int qg  = qw0 + qf * 16 + l15;
                        if (kvg > qg) sacc[kvf][qf][j] = -3e38f;
                    }
        }

        // online softmax per qf (row q = l15; kv spread over kvf, j, l4)
        #pragma unroll
        for (int qf = 0; qf < 2; qf++) {
            float mx = -3e38f;
            #pragma unroll
            for (int kvf = 0; kvf < 4; kvf++)
                #pragma unroll
                for (int j = 0; j < 4; j++) mx = fmaxf(mx, sacc[kvf][qf][j]);
            mx = fmaxf(mx, __shfl_xor(mx, 16));
            mx = fmaxf(mx, __shfl_xor(mx, 32));
            float mnew = fmaxf(m_s[qf], mx);
            bool need = __any(mx > m_s[qf]);
            float mc = mnew * c1;
            float rs = 0.f;
            #pragma unroll
            for (int kvf = 0; kvf < 4; kvf++)
                #pragma unroll
                for (int j = 0; j < 4; j++) {
                    float p = exp2f(fmaf(sacc[kvf][qf][j], c1, -mc));
                    sacc[kvf][qf][j] = p;
                    rs += p;
                }
            rs += __shfl_xor(rs, 16);
            rs += __shfl_xor(rs, 32);
            if (need) {
                float scf = exp2f((m_s[qf] - mnew) * c1);
                #pragma unroll
                for (int df = 0; df < 4; df++) oacc[df][qf] *= scf;
                l_s[qf] = l_s[qf] * scf + rs;
                m_s[qf] = mnew;
            } else {
                l_s[qf] += rs;
            }
            // pack P -> LDS (row q, contiguous kv)
            #pragma unroll
            for (int kvf = 0; kvf < 4; kvf++) {
                u32x2 pr;
                pr[0] = cvt_pk_bf16(sacc[kvf][qf][0], sacc[kvf][qf][1]);
                pr[1] = cvt_pk_bf16(sacc[kvf][qf][2], sacc[kvf][qf][3]);
                *(u32x2*)&P_lds[w][qf * 16 + l15][kvf * 16 + l4 * 4] = pr;
            }
        }
        asm volatile("s_waitcnt lgkmcnt(0)" ::: "memory");
        __builtin_amdgcn_sched_barrier(0);

        bf16x8 pf[2][2];
        #pragma unroll
        for (int qf = 0; qf < 2; qf++)
            #pragma unroll
            for (int ks = 0; ks < 2; ks++)
                pf[qf][ks] = *(const bf16x8*)&P_lds[w][qf * 16 + l15][ks * 32 + l4 * 8];

        // O^T += Vt * P^T : D[d][q]
        #pragma unroll
        for (int df = 0; df < 4; df++) {
            bf16x8 v0 = *(const bf16x8*)&Vg[(size_t)(df * 16 + l15) * 2048 + kv0 + l4 * 8];
            bf16x8 v1 = *(const bf16x8*)&Vg[(size_t)(df * 16 + l15) * 2048 + kv0 + 32 + l4 * 8];
            #pragma unroll
            for (int qf = 0; qf < 2; qf++) {
                oacc[df][qf] = __builtin_amdgcn_mfma_f32_16x16x32_bf16(v0, pf[qf][0], oacc[df][qf], 0, 0, 0);
                oacc[df][qf] = __builtin_amdgcn_mfma_f32_16x16x32_bf16(v1, pf[qf][1], oacc[df][qf], 0, 0, 0);
            }
        }
    }

    // epilogue: O[q][d] = oacc/l, repack via LDS, coalesced store
    float rl[2] = {1.f / l_s[0], 1.f / l_s[1]};
    #pragma unroll
    for (int df = 0; df < 4; df++)
        #pragma unroll
        for (int qf = 0; qf < 2; qf++) {
            u32x2 pr;
            pr[0] = cvt_pk_bf16(oacc[df][qf][0] * rl[qf], oacc[df][qf][1] * rl[qf]);
            pr[1] = cvt_pk_bf16(oacc[df][qf][2] * rl[qf], oacc[df][qf][3] * rl[qf]);
            *(u32x2*)&P_lds[w][qf * 16 + l15][df * 16 + l4 * 4] = pr;
        }
    asm volatile("s_waitcnt lgkmcnt(0)" ::: "memory");
    __builtin_amdgcn_sched_barrier(0);
    {
        const int r = lane >> 1, half = lane & 1;
        size_t orow = (size_t)(b * 2048 + qw0 + r) * 1024 + h * 64 + half * 32;
        #pragma unroll
        for (int i = 0; i < 4; i++)
            *(bf16x8*)&Aout[orow + i * 8] = *(const bf16x8*)&P_lds[w][r][half * 32 + i * 8];
    }
}

// ---------------------------------------------------------------------------
extern "C" void kernel_launch(void* const* d_in, const int* in_sizes, int n_in,
                              void* d_out, int out_size, void* d_ws, size_t ws_size,
                              hipStream_t stream) {
    const float* x  = (const float*)d_in[0];
    const float* Wq = (const float*)d_in[1];
    const float* Wk = (const float*)d_in[2];
    const float* Wv = (const float*)d_in[3];
    const float* Wo = (const float*)d_in[4];
    float* out = (float*)d_out;

    const size_t NX = (size_t)8192 * 1024;   // 8.4M elems
    const size_t NW = (size_t)1024 * 1024;   // 1M elems
    short* xb  = (short*)d_ws;               // 16MB
    short* Wqb = xb  + NX;                   // 2MB each
    short* Wkb = Wqb + NW;
    short* Wvb = Wkb + NW;
    short* Wob = Wvb + NW;
    short* Qw  = Wob + NW;                   // 16MB
    short* Kw  = Qw + NX;                    // 16MB  -> ws total 56MB
    short* Vw  = (short*)d_out;              // d_out lower 16MB (scratch until gemm_out)
    short* Vt  = Vw + NX;                    // d_out upper 16MB
    short* Aw  = xb;                         // xb dead after gemm_qkv

    hipLaunchKernelGGL(convert_kernel, dim3(NX / 2048), dim3(256), 0, stream, x,  xb);
    hipLaunchKernelGGL(convert_kernel, dim3(NW / 2048), dim3(256), 0, stream, Wq, Wqb);
    hipLaunchKernelGGL(convert_kernel, dim3(NW / 2048), dim3(256), 0, stream, Wk, Wkb);
    hipLaunchKernelGGL(convert_kernel, dim3(NW / 2048), dim3(256), 0, stream, Wv, Wvb);
    hipLaunchKernelGGL(convert_kernel, dim3(NW / 2048), dim3(256), 0, stream, Wo, Wob);

    hipLaunchKernelGGL(gemm_qkv, dim3(8, 64, 3), dim3(256), 0, stream, xb, Wqb, Wkb, Wvb, Qw, Kw, Vw);
    hipLaunchKernelGGL(transpose_v, dim3(32, 64), dim3(256), 0, stream, Vw, Vt);
    hipLaunchKernelGGL(attn_kernel, dim3(16, 64), dim3(256), 0, stream, Qw, Kw, Vt, Aw);
    hipLaunchKernelGGL(gemm_out, dim3(8, 64), dim3(256), 0, stream, Aw, Wob, out);
}

// Round 4
// 214.516 us; speedup vs baseline: 2.0588x; 1.7924x over previous
//
#include <hip/hip_runtime.h>
#include <hip/hip_bf16.h>
#include <cstdint>
#include <cstddef>

// MHA B=4 S=2048 D=1024 H=16 hd=64 causal.
// convert x,W->bf16 | QKV GEMM (global_load_lds) | V transpose | flash attn (8-wave block,
// LDS-staged K/V, XOR-swizzle, dbuf prefetch) | out GEMM.
// ws: xb(16M) Wb(8M) Qw(16M) Kw(16M) = 56MB. Vw/Vt in d_out halves; Aw aliases xb.

typedef short bf16x8 __attribute__((ext_vector_type(8)));
typedef float f32x4 __attribute__((ext_vector_type(4)));
typedef unsigned int u32x2 __attribute__((ext_vector_type(2)));

__device__ __forceinline__ short f2bf(float f) {
    union { float f; uint32_t u; } c; c.f = f;
    uint32_t r = c.u + 0x7fffu + ((c.u >> 16) & 1u);   // RNE
    return (short)(r >> 16);
}

__device__ __forceinline__ unsigned cvt_pk_bf16(float lo, float hi) {
    unsigned r;
    asm("v_cvt_pk_bf16_f32 %0, %1, %2" : "=v"(r) : "v"(lo), "v"(hi));
    return r;
}

#define GLOAD_LDS16(g, l) __builtin_amdgcn_global_load_lds( \
    (const __attribute__((address_space(1))) void*)(g),     \
    (__attribute__((address_space(3))) void*)(l), 16, 0, 0)

// ---------------------------------------------------------------------------
// f32 -> bf16 convert, 8 elems/thread
// ---------------------------------------------------------------------------
__global__ __launch_bounds__(256) void convert_kernel(const float* __restrict__ src,
                                                      short* __restrict__ dst) {
    int i = blockIdx.x * 256 + threadIdx.x;
    const float4* s = (const float4*)src + (size_t)i * 2;
    float4 v0 = s[0], v1 = s[1];
    bf16x8 o;
    o[0] = f2bf(v0.x); o[1] = f2bf(v0.y); o[2] = f2bf(v0.z); o[3] = f2bf(v0.w);
    o[4] = f2bf(v1.x); o[5] = f2bf(v1.y); o[6] = f2bf(v1.z); o[7] = f2bf(v1.w);
    *((bf16x8*)dst + i) = o;
}

// ---------------------------------------------------------------------------
// GEMM body: Out[gridDim.y*128, 1024] = A[., 1024](bf16) * Bw[1024,1024]^T (bf16)
// 128x128 tile, BK=32, 4 waves (2x2), global_load_lds staging (linear LDS).
// ---------------------------------------------------------------------------
template<bool OUT_F32>
__device__ __forceinline__ void gemm_body(const short* __restrict__ A,
                                          const short* __restrict__ Bw,
                                          void* __restrict__ Outp) {
    __shared__ short As[128 * 32];
    __shared__ short Bs[128 * 32];
    const int tid = threadIdx.x;
    const int lane = tid & 63, w = tid >> 6;
    const int wr = w >> 1, wc = w & 1;
    const int l15 = lane & 15, l4 = lane >> 4;
    const size_t m0 = (size_t)blockIdx.y * 128;
    const size_t n0 = (size_t)blockIdx.x * 128;

    f32x4 acc[4][4];
    const f32x4 zf = {0.f, 0.f, 0.f, 0.f};
    #pragma unroll
    for (int i = 0; i < 4; i++)
        #pragma unroll
        for (int j = 0; j < 4; j++) acc[i][j] = zf;

    for (int k0 = 0; k0 < 1024; k0 += 32) {
        #pragma unroll
        for (int r = 0; r < 2; r++) {
            int c = r * 256 + tid;
            int row = c >> 2, q = c & 3;
            GLOAD_LDS16(A  + (m0 + row) * 1024 + k0 + q * 8, &As[(r * 256 + w * 64) * 8]);
            GLOAD_LDS16(Bw + (n0 + row) * 1024 + k0 + q * 8, &Bs[(r * 256 + w * 64) * 8]);
        }
        __syncthreads();

        bf16x8 af[4], bfr[4];
        #pragma unroll
        for (int mi = 0; mi < 4; mi++)
            af[mi] = *(const bf16x8*)&As[(wr * 64 + mi * 16 + l15) * 32 + l4 * 8];
        #pragma unroll
        for (int ni = 0; ni < 4; ni++)
            bfr[ni] = *(const bf16x8*)&Bs[(wc * 64 + ni * 16 + l15) * 32 + l4 * 8];
        #pragma unroll
        for (int mi = 0; mi < 4; mi++)
            #pragma unroll
            for (int ni = 0; ni < 4; ni++)
                acc[mi][ni] = __builtin_amdgcn_mfma_f32_16x16x32_bf16(af[mi], bfr[ni], acc[mi][ni], 0, 0, 0);
        __syncthreads();
    }

    #pragma unroll
    for (int mi = 0; mi < 4; mi++) {
        #pragma unroll
        for (int ni = 0; ni < 4; ni++) {
            size_t row = m0 + wr * 64 + mi * 16 + (l4 << 2);
            size_t col = n0 + wc * 64 + ni * 16 + l15;
            #pragma unroll
            for (int j = 0; j < 4; j++) {
                float v = acc[mi][ni][j];
                if (OUT_F32) ((float*)Outp)[(row + j) * 1024 + col] = v;
                else         ((short*)Outp)[(row + j) * 1024 + col] = f2bf(v);
            }
        }
    }
}

__global__ __launch_bounds__(256) void gemm_qkv(const short* __restrict__ xb,
                                                const short* __restrict__ Wq,
                                                const short* __restrict__ Wk,
                                                const short* __restrict__ Wv,
                                                short* __restrict__ Q,
                                                short* __restrict__ K,
                                                short* __restrict__ V) {
    const short* Bw = (blockIdx.z == 0) ? Wq : (blockIdx.z == 1) ? Wk : Wv;
    short* Out      = (blockIdx.z == 0) ? Q  : (blockIdx.z == 1) ? K  : V;
    gemm_body<false>(xb, Bw, Out);
}

__global__ __launch_bounds__(256) void gemm_out(const short* __restrict__ Aw,
                                                const short* __restrict__ Wo,
                                                float* __restrict__ Out) {
    gemm_body<true>(Aw, Wo, Out);
}

// ---------------------------------------------------------------------------
// V transpose: Vt[(bh*64+d)*2048 + s] = Vw[(b*2048+s)*1024 + h*64 + d]
// ---------------------------------------------------------------------------
__global__ __launch_bounds__(256) void transpose_v(const short* __restrict__ Vw,
                                                   short* __restrict__ Vt) {
    __shared__ short T[64][72];
    const int tid = threadIdx.x;
    const int s0 = blockIdx.x * 64;
    const int bh = blockIdx.y, b = bh >> 4, h = bh & 15;
    const int r = tid >> 2, c = tid & 3;
    const size_t srow = (size_t)(b * 2048 + s0 + r) * 1024 + h * 64 + c * 16;
    *(bf16x8*)&T[r][c * 16]     = *(const bf16x8*)&Vw[srow];
    *(bf16x8*)&T[r][c * 16 + 8] = *(const bf16x8*)&Vw[srow + 8];
    __syncthreads();
    short tmp[16];
    #pragma unroll
    for (int i = 0; i < 16; i++) tmp[i] = T[c * 16 + i][r];
    bf16x8 o0, o1;
    #pragma unroll
    for (int i = 0; i < 8; i++) { o0[i] = tmp[i]; o1[i] = tmp[8 + i]; }
    size_t orow = (size_t)(bh * 64 + r) * 2048 + s0 + c * 16;
    *(bf16x8*)&Vt[orow] = o0;
    *(bf16x8*)&Vt[orow + 8] = o1;
}

// ---------------------------------------------------------------------------
// Flash attn, causal, 8 waves/block covering 256 q-rows; KVBLK=64.
// K/V staged once per block into XOR-swizzled LDS (pre-swizzled global src,
// linear global_load_lds dest), double-buffered, prefetch before compute.
// grid (bh=64, qblk=8, heavy-first). Q/K: [8192][1024]; Vt: [bh*64+d][2048].
// ---------------------------------------------------------------------------
__global__ __launch_bounds__(512, 4) void attn_kernel(const short* __restrict__ Q,
                                                      const short* __restrict__ K,
                                                      const short* __restrict__ Vt,
                                                      short* __restrict__ Aout) {
    __shared__ __align__(16) short K_lds[2][64 * 64];   // [kv][d], swizzled
    __shared__ __align__(16) short V_lds[2][64 * 64];   // [d][s_local], swizzled
    __shared__ __align__(16) short P_lds[8][32][72];
    const int tid = threadIdx.x;
    const int lane = tid & 63, w = tid >> 6;
    const int l15 = lane & 15, l4 = lane >> 4;
    const int bh = blockIdx.x, b = bh >> 4, h = bh & 15;
    const int qblk = 7 - blockIdx.y;                    // heavy blocks dispatch first
    const int qw0 = qblk * 256 + w * 32;
    const short* Qg = Q + (size_t)b * 2048 * 1024 + h * 64;
    const short* Kg = K + (size_t)b * 2048 * 1024 + h * 64;
    const short* Vg = Vt + (size_t)bh * 64 * 2048;
    const float c1 = 0.18033688011112042f;              // 0.125 * log2(e)

    // staging geometry: wave w fills rows [w*8, w*8+8) of the 64x64 tile;
    // lane covers row w*8+(lane>>3), 16B chunk (lane&7); source col chunk
    // pre-swizzled by ^(row&7) so linear LDS + swizzled read match (rule #21).
    const int srow = (lane >> 3);                        // 0..7 (row within wave's 8)
    const int scol = ((lane & 7) ^ srow) * 8;            // bf16 col of 16B chunk

    bf16x8 qfr[2][2];
    #pragma unroll
    for (int qf = 0; qf < 2; qf++)
        #pragma unroll
        for (int ks = 0; ks < 2; ks++)
            qfr[qf][ks] = *(const bf16x8*)&Qg[(size_t)(qw0 + qf * 16 + l15) * 1024 + ks * 32 + l4 * 8];

    const f32x4 zf = {0.f, 0.f, 0.f, 0.f};
    f32x4 oacc[4][2];                                    // [df][qf]: O^T[d][q]
    float m_s[2] = {-3e38f, -3e38f}, l_s[2] = {0.f, 0.f};
    #pragma unroll
    for (int df = 0; df < 4; df++)
        #pragma unroll
        for (int qf = 0; qf < 2; qf++) oacc[df][qf] = zf;

    const int lim = 4 * qblk + 3;                        // block-level last tile

    // swizzled LDS read: row r, byte-col cb -> base + r*128 + (cb ^ ((r&7)<<4))
#define KV_RD(base, r, cb) (*(const bf16x8*)((const char*)(base) + (r) * 128 + ((cb) ^ (((r) & 7) << 4))))

    // prologue: stage tile 0 into buf 0
    GLOAD_LDS16(Kg + (size_t)(w * 8 + srow) * 1024 + scol, &K_lds[0][w * 512]);
    GLOAD_LDS16(Vg + (size_t)(w * 8 + srow) * 2048 + scol, &V_lds[0][w * 512]);
    __syncthreads();

    int buf = 0;
    for (int t = 0; t <= lim; ++t) {
        const int kv0 = t * 64;
        if (t < lim) {                                   // prefetch next tile (issue early)
            const int nv0 = kv0 + 64;
            GLOAD_LDS16(Kg + (size_t)(nv0 + w * 8 + srow) * 1024 + scol, &K_lds[buf ^ 1][w * 512]);
            GLOAD_LDS16(Vg + (size_t)(w * 8 + srow) * 2048 + nv0 + scol, &V_lds[buf ^ 1][w * 512]);
        }

        const int lim_w = (qw0 + 31) >> 6;               // wave's last needed tile
        if (t <= lim_w) {
            const short* Kb = K_lds[buf];
            const short* Vb = V_lds[buf];

            // S^T = K * Q^T : D[kv][q]
            f32x4 sacc[4][2];
            #pragma unroll
            for (int kvf = 0; kvf < 4; kvf++)
                #pragma unroll
                for (int qf = 0; qf < 2; qf++) sacc[kvf][qf] = zf;
            #pragma unroll
            for (int kvf = 0; kvf < 4; kvf++) {
                bf16x8 kf0 = KV_RD(Kb, kvf * 16 + l15, l4 * 16);
                bf16x8 kf1 = KV_RD(Kb, kvf * 16 + l15, 64 + l4 * 16);
                #pragma unroll
                for (int qf = 0; qf < 2; qf++) {
                    sacc[kvf][qf] = __builtin_amdgcn_mfma_f32_16x16x32_bf16(kf0, qfr[qf][0], sacc[kvf][qf], 0, 0, 0);
                    sacc[kvf][qf] = __builtin_amdgcn_mfma_f32_16x16x32_bf16(kf1, qfr[qf][1], sacc[kvf][qf], 0, 0, 0);
                }
            }

            if (t == lim_w) {                            // causal mask on diagonal tile
                #pragma unroll
                for (int kvf = 0; kvf < 4; kvf++)
                    #pragma unroll
                    for (int qf = 0; qf < 2; qf++)
                        #pragma unroll
                        for (int j = 0; j < 4; j++) {
                            int kvg = kv0 + kvf * 16 + l4 * 4 + j;
                            int qg  = qw0 + qf * 16 + l15;
                            if (kvg > qg) sacc[kvf][qf][j] = -3e38f;
                        }
            }

            // online softmax per qf (row q = l15; kv spread over kvf, j, l4)
            #pragma unroll
            for (int qf = 0; qf < 2; qf++) {
                float mx = -3e38f;
                #pragma unroll
                for (int kvf = 0; kvf < 4; kvf++)
                    #pragma unroll
                    for (int j = 0; j < 4; j++) mx = fmaxf(mx, sacc[kvf][qf][j]);
                mx = fmaxf(mx, __shfl_xor(mx, 16));
                mx = fmaxf(mx, __shfl_xor(mx, 32));
                float mnew = fmaxf(m_s[qf], mx);
                bool need = __any(mx > m_s[qf]);
                float mc = mnew * c1;
                float rs = 0.f;
                #pragma unroll
                for (int kvf = 0; kvf < 4; kvf++)
                    #pragma unroll
                    for (int j = 0; j < 4; j++) {
                        float p = exp2f(fmaf(sacc[kvf][qf][j], c1, -mc));
                        sacc[kvf][qf][j] = p;
                        rs += p;
                    }
                rs += __shfl_xor(rs, 16);
                rs += __shfl_xor(rs, 32);
                if (need) {
                    float scf = exp2f((m_s[qf] - mnew) * c1);
                    #pragma unroll
                    for (int df = 0; df < 4; df++) oacc[df][qf] *= scf;
                    l_s[qf] = l_s[qf] * scf + rs;
                    m_s[qf] = mnew;
                } else {
                    l_s[qf] += rs;
                }
                #pragma unroll
                for (int kvf = 0; kvf < 4; kvf++) {
                    u32x2 pr;
                    pr[0] = cvt_pk_bf16(sacc[kvf][qf][0], sacc[kvf][qf][1]);
                    pr[1] = cvt_pk_bf16(sacc[kvf][qf][2], sacc[kvf][qf][3]);
                    *(u32x2*)&P_lds[w][qf * 16 + l15][kvf * 16 + l4 * 4] = pr;
                }
            }
            asm volatile("s_waitcnt lgkmcnt(0)" ::: "memory");
            __builtin_amdgcn_sched_barrier(0);

            bf16x8 pf[2][2];
            #pragma unroll
            for (int qf = 0; qf < 2; qf++)
                #pragma unroll
                for (int ks = 0; ks < 2; ks++)
                    pf[qf][ks] = *(const bf16x8*)&P_lds[w][qf * 16 + l15][ks * 32 + l4 * 8];

            // O^T += Vt * P^T : D[d][q]
            #pragma unroll
            for (int df = 0; df < 4; df++) {
                bf16x8 v0 = KV_RD(Vb, df * 16 + l15, l4 * 16);
                bf16x8 v1 = KV_RD(Vb, df * 16 + l15, 64 + l4 * 16);
                #pragma unroll
                for (int qf = 0; qf < 2; qf++) {
                    oacc[df][qf] = __builtin_amdgcn_mfma_f32_16x16x32_bf16(v0, pf[qf][0], oacc[df][qf], 0, 0, 0);
                    oacc[df][qf] = __builtin_amdgcn_mfma_f32_16x16x32_bf16(v1, pf[qf][1], oacc[df][qf], 0, 0, 0);
                }
            }
        }
        __syncthreads();                                 // drains vmcnt (prefetch) + lgkm
        buf ^= 1;
    }

    // epilogue: O[q][d] = oacc/l, repack via LDS, coalesced store
    float rl[2] = {1.f / l_s[0], 1.f / l_s[1]};
    #pragma unroll
    for (int df = 0; df < 4; df++)
        #pragma unroll
        for (int qf = 0; qf < 2; qf++) {
            u32x2 pr;
            pr[0] = cvt_pk_bf16(oacc[df][qf][0] * rl[qf], oacc[df][qf][1] * rl[qf]);
            pr[1] = cvt_pk_bf16(oacc[df][qf][2] * rl[qf], oacc[df][qf][3] * rl[qf]);
            *(u32x2*)&P_lds[w][qf * 16 + l15][df * 16 + l4 * 4] = pr;
        }
    asm volatile("s_waitcnt lgkmcnt(0)" ::: "memory");
    __builtin_amdgcn_sched_barrier(0);
    {
        const int r = lane >> 1, half = lane & 1;
        size_t orow = (size_t)(b * 2048 + qw0 + r) * 1024 + h * 64 + half * 32;
        #pragma unroll
        for (int i = 0; i < 4; i++)
            *(bf16x8*)&Aout[orow + i * 8] = *(const bf16x8*)&P_lds[w][r][half * 32 + i * 8];
    }
#undef KV_RD
}

// ---------------------------------------------------------------------------
extern "C" void kernel_launch(void* const* d_in, const int* in_sizes, int n_in,
                              void* d_out, int out_size, void* d_ws, size_t ws_size,
                              hipStream_t stream) {
    const float* x  = (const float*)d_in[0];
    const float* Wq = (const float*)d_in[1];
    const float* Wk = (const float*)d_in[2];
    const float* Wv = (const float*)d_in[3];
    const float* Wo = (const float*)d_in[4];
    float* out = (float*)d_out;

    const size_t NX = (size_t)8192 * 1024;
    const size_t NW = (size_t)1024 * 1024;
    short* xb  = (short*)d_ws;               // 16MB
    short* Wqb = xb  + NX;
    short* Wkb = Wqb + NW;
    short* Wvb = Wkb + NW;
    short* Wob = Wvb + NW;
    short* Qw  = Wob + NW;                   // 16MB
    short* Kw  = Qw + NX;                    // 16MB -> ws total 56MB
    short* Vw  = (short*)d_out;              // d_out lower half (scratch until gemm_out)
    short* Vt  = Vw + NX;                    // d_out upper half
    short* Aw  = xb;                         // xb dead after gemm_qkv

    hipLaunchKernelGGL(convert_kernel, dim3(NX / 2048), dim3(256), 0, stream, x,  xb);
    hipLaunchKernelGGL(convert_kernel, dim3(NW / 2048), dim3(256), 0, stream, Wq, Wqb);
    hipLaunchKernelGGL(convert_kernel, dim3(NW / 2048), dim3(256), 0, stream, Wk, Wkb);
    hipLaunchKernelGGL(convert_kernel, dim3(NW / 2048), dim3(256), 0, stream, Wv, Wvb);
    hipLaunchKernelGGL(convert_kernel, dim3(NW / 2048), dim3(256), 0, stream, Wo, Wob);

    hipLaunchKernelGGL(gemm_qkv, dim3(8, 64, 3), dim3(256), 0, stream, xb, Wqb, Wkb, Wvb, Qw, Kw, Vw);
    hipLaunchKernelGGL(transpose_v, dim3(32, 64), dim3(256), 0, stream, Vw, Vt);
    hipLaunchKernelGGL(attn_kernel, dim3(64, 8), dim3(512), 0, stream, Qw, Kw, Vt, Aw);
    hipLaunchKernelGGL(gemm_out, dim3(8, 64), dim3(256), 0, stream, Aw, Wob, out);
}